// Round 1
// baseline (170.255 us; speedup 1.0000x reference)
//
#include <hip/hip_runtime.h>

// out[i] = floor(image[i] * 0.5f)  — elementwise, memory-bound.
// image: 8*3*1024*1024 fp32. text_bits is unused by the reference arithmetic.

__global__ __launch_bounds__(256) void stego_halve_f4(const float4* __restrict__ in,
                                                      float4* __restrict__ out,
                                                      int n4) {
    int i = blockIdx.x * blockDim.x + threadIdx.x;
    if (i < n4) {
        float4 v = in[i];
        float4 r;
        r.x = floorf(v.x * 0.5f);
        r.y = floorf(v.y * 0.5f);
        r.z = floorf(v.z * 0.5f);
        r.w = floorf(v.w * 0.5f);
        out[i] = r;
    }
}

__global__ __launch_bounds__(256) void stego_halve_tail(const float* __restrict__ in,
                                                        float* __restrict__ out,
                                                        int start, int n) {
    int i = start + blockIdx.x * blockDim.x + threadIdx.x;
    if (i < n) {
        out[i] = floorf(in[i] * 0.5f);
    }
}

extern "C" void kernel_launch(void* const* d_in, const int* in_sizes, int n_in,
                              void* d_out, int out_size, void* d_ws, size_t ws_size,
                              hipStream_t stream) {
    const float* image = (const float*)d_in[0];
    float* out = (float*)d_out;
    int n = in_sizes[0];   // 25,165,824

    int n4 = n / 4;        // divisible: 6,291,456 float4s
    int tail_start = n4 * 4;

    if (n4 > 0) {
        int block = 256;
        int grid = (n4 + block - 1) / block;
        stego_halve_f4<<<grid, block, 0, stream>>>((const float4*)image, (float4*)out, n4);
    }
    if (tail_start < n) {
        int rem = n - tail_start;
        int block = 256;
        int grid = (rem + block - 1) / block;
        stego_halve_tail<<<grid, block, 0, stream>>>(image, out, tail_start, n);
    }
}

// Round 3
// 167.286 us; speedup vs baseline: 1.0177x; 1.0177x over previous
//
#include <hip/hip_runtime.h>

// out[i] = floor(image[i] * 0.5f) — pure elementwise stream, memory-bound.
// image: 8*3*1024*1024 fp32 (25,165,824 elements, divisible by 16).
// Compulsory traffic: 96 MiB read + 96 MiB write ≈ 201 MB → ~32 µs @ 6.3 TB/s.
// Streaming data, zero reuse → nontemporal loads/stores.
// NOTE: __builtin_nontemporal_* rejects HIP_vector_type structs; use a native
// clang ext_vector_type float4 (identical 16B layout/alignment).

typedef float vfloat4 __attribute__((ext_vector_type(4)));

__global__ __launch_bounds__(256) void stego_halve_stream(const vfloat4* __restrict__ in,
                                                          vfloat4* __restrict__ out,
                                                          int n4) {
    const int stride = gridDim.x * blockDim.x;
    int i = blockIdx.x * blockDim.x + threadIdx.x;
    // 4 float4s per thread via grid-stride; each iteration fully coalesced
    // (consecutive lanes -> consecutive 16B).
    #pragma unroll 4
    for (; i < n4; i += stride) {
        vfloat4 v = __builtin_nontemporal_load(&in[i]);
        vfloat4 r;
        r.x = floorf(v.x * 0.5f);
        r.y = floorf(v.y * 0.5f);
        r.z = floorf(v.z * 0.5f);
        r.w = floorf(v.w * 0.5f);
        __builtin_nontemporal_store(r, &out[i]);
    }
}

__global__ __launch_bounds__(256) void stego_halve_tail(const float* __restrict__ in,
                                                        float* __restrict__ out,
                                                        int start, int n) {
    int i = start + blockIdx.x * blockDim.x + threadIdx.x;
    if (i < n) {
        out[i] = floorf(in[i] * 0.5f);
    }
}

extern "C" void kernel_launch(void* const* d_in, const int* in_sizes, int n_in,
                              void* d_out, int out_size, void* d_ws, size_t ws_size,
                              hipStream_t stream) {
    const float* image = (const float*)d_in[0];
    float* out = (float*)d_out;
    int n = in_sizes[0];   // 25,165,824

    int n4 = n / 4;        // 6,291,456 float4s
    int tail_start = n4 * 4;

    if (n4 > 0) {
        const int block = 256;
        // 4 float4s (64 B) per thread: ~6144 blocks = 24 blocks/CU — enough
        // waves to saturate HBM, small dispatch tail.
        int threads_needed = (n4 + 3) / 4;
        int grid = (threads_needed + block - 1) / block;
        stego_halve_stream<<<grid, block, 0, stream>>>((const vfloat4*)image,
                                                       (vfloat4*)out, n4);
    }
    if (tail_start < n) {
        int rem = n - tail_start;
        const int block = 256;
        int grid = (rem + block - 1) / block;
        stego_halve_tail<<<grid, block, 0, stream>>>(image, out, tail_start, n);
    }
}